// Round 1
// baseline (3670.739 us; speedup 1.0000x reference)
//
#include <hip/hip_runtime.h>
#include <hip/hip_bf16.h>

typedef __attribute__((ext_vector_type(4))) float f32x4;
typedef __attribute__((ext_vector_type(8))) short bf16x8;

#define NB 1024   // batch
#define ND 128    // time steps
#define NI 64     // input dim
#define NH 256    // dec hidden
#define NHE 512   // enc hidden
#define KENC 576  // NI + NHE
#define NENC 2048 // 4*NHE
#define KDEC 256
#define NDEC 1152 // 1024 gate cols + 64 projection cols + 64 zero pad

__device__ __forceinline__ float sigmf(float x) { return 1.0f / (1.0f + expf(-x)); }

__device__ __forceinline__ f32x4 mfma16(bf16x8 a, bf16x8 b, f32x4 c) {
    return __builtin_amdgcn_mfma_f32_16x16x32_bf16(a, b, c, 0, 0, 0);
}

// ---------------- packing kernels ----------------

// Wp[n'][k], n' = 4*j + g  (gate-interleaved, transposed). rows 0..63 of K = Wx, 64..575 = Wh.
__global__ void pack_enc_kernel(const float* __restrict__ Wx, const float* __restrict__ Wh,
                                const float* __restrict__ bsrc,
                                __hip_bfloat16* __restrict__ Wp, float* __restrict__ bp)
{
    int n = blockIdx.y;                       // 0..2047
    int k = blockIdx.x * 256 + threadIdx.x;   // 0..767 (guard 576)
    int j = n >> 2, g = n & 3;
    int col = g * NHE + j;
    if (k < KENC) {
        float v = (k < NI) ? Wx[k * NENC + col] : Wh[(k - NI) * NENC + col];
        Wp[(size_t)n * KENC + k] = __float2bfloat16(v);
    }
    if (blockIdx.x == 0 && threadIdx.x == 0) bp[n] = bsrc[col];
}

// rows 0..1023: dec gates (transposed, interleaved); 1024..1087: out_w^T; 1088..1151: zeros
__global__ void pack_dec_kernel(const float* __restrict__ Wh, const float* __restrict__ ow,
                                const float* __restrict__ bsrc,
                                __hip_bfloat16* __restrict__ Wp, float* __restrict__ bp)
{
    int n = blockIdx.y;          // 0..1151
    int k = threadIdx.x;         // 0..255
    float v;
    if (n < 1024) {
        int j = n >> 2, g = n & 3;
        int col = g * NH + j;
        v = Wh[k * 1024 + col];
        if (k == 0) bp[n] = bsrc[col];
    } else if (n < 1088) {
        v = ow[k * NI + (n - 1024)];
    } else {
        v = 0.0f;
    }
    Wp[(size_t)n * KDEC + k] = __float2bfloat16(v);
}

// X_imp, time-major bf16: Xb[d][b][i]
__global__ void pack_xb_kernel(const float* __restrict__ X, const int* __restrict__ W,
                               const float* __restrict__ A, __hip_bfloat16* __restrict__ Xb)
{
    int idx = blockIdx.x * 256 + threadIdx.x;  // < 8388608, enumerates dest [d][b][i]
    int i = idx & 63;
    int t1 = idx >> 6;
    int b = t1 & 1023;
    int d = t1 >> 10;
    int src = (b * ND + d) * NI + i;
    float v = W[src] ? X[src] : A[d * NI + i];
    Xb[idx] = __float2bfloat16(v);
}

// ---------------- encoder step ----------------
// gates[1024][2048'] = [Xt | h] @ Wp^T, then peephole update fused.
// grid (16 m-tiles, 16 n-tiles), 256 threads (4 waves). Block tile 64 x 128.
__global__ __launch_bounds__(256) void enc_step_kernel(
    const __hip_bfloat16* __restrict__ Xt,
    const __hip_bfloat16* __restrict__ h_in,
    __hip_bfloat16* __restrict__ h_out,
    float* __restrict__ c,
    const __hip_bfloat16* __restrict__ Wp,
    const float* __restrict__ bp,
    const float* __restrict__ pi, const float* __restrict__ pf, const float* __restrict__ po)
{
    __shared__ float glds[64 * 128];
    const int tid  = threadIdx.x;
    const int lane = tid & 63;
    const int wv   = tid >> 6;
    const int m0   = blockIdx.x * 64;
    const int lr   = lane & 15;
    const int lk   = (lane >> 4) << 3;

    f32x4 acc[4][2];
    #pragma unroll
    for (int mi = 0; mi < 4; ++mi)
        #pragma unroll
        for (int ni = 0; ni < 2; ++ni) acc[mi][ni] = {0.f, 0.f, 0.f, 0.f};

    const __hip_bfloat16* wb = Wp + (size_t)(blockIdx.y * 128 + wv * 32 + lr) * KENC + lk;
    const __hip_bfloat16* xb = Xt + (size_t)(m0 + lr) * NI + lk;
    const __hip_bfloat16* hb = h_in + (size_t)(m0 + lr) * NHE + lk;

    // X part: K 0..63
    #pragma unroll
    for (int kk = 0; kk < NI; kk += 32) {
        bf16x8 a[4], bf[2];
        #pragma unroll
        for (int mi = 0; mi < 4; ++mi)
            a[mi] = *reinterpret_cast<const bf16x8*>(xb + mi * 16 * NI + kk);
        #pragma unroll
        for (int ni = 0; ni < 2; ++ni)
            bf[ni] = *reinterpret_cast<const bf16x8*>(wb + ni * 16 * KENC + kk);
        #pragma unroll
        for (int mi = 0; mi < 4; ++mi)
            #pragma unroll
            for (int ni = 0; ni < 2; ++ni)
                acc[mi][ni] = mfma16(a[mi], bf[ni], acc[mi][ni]);
    }
    // h part: K 64..575
    #pragma unroll 4
    for (int kk = 0; kk < NHE; kk += 32) {
        bf16x8 a[4], bf[2];
        #pragma unroll
        for (int mi = 0; mi < 4; ++mi)
            a[mi] = *reinterpret_cast<const bf16x8*>(hb + mi * 16 * NHE + kk);
        #pragma unroll
        for (int ni = 0; ni < 2; ++ni)
            bf[ni] = *reinterpret_cast<const bf16x8*>(wb + ni * 16 * KENC + NI + kk);
        #pragma unroll
        for (int mi = 0; mi < 4; ++mi)
            #pragma unroll
            for (int ni = 0; ni < 2; ++ni)
                acc[mi][ni] = mfma16(a[mi], bf[ni], acc[mi][ni]);
    }

    // epilogue: transpose via LDS, then peephole update (gate order i,f,c,o)
    #pragma unroll
    for (int mi = 0; mi < 4; ++mi)
        #pragma unroll
        for (int ni = 0; ni < 2; ++ni)
            #pragma unroll
            for (int v = 0; v < 4; ++v)
                glds[(16 * mi + ((lane >> 4) << 2) + v) * 128 + wv * 32 + ni * 16 + lr] = acc[mi][ni][v];
    __syncthreads();

    for (int idx = tid; idx < 64 * 32; idx += 256) {
        int r = idx >> 5, j = idx & 31;
        int jg = blockIdx.y * 32 + j;
        float4 g  = *reinterpret_cast<const float4*>(&glds[r * 128 + 4 * j]);
        float4 bb = *reinterpret_cast<const float4*>(&bp[4 * jg]);
        int ci = (m0 + r) * NHE + jg;
        float c_old = c[ci];
        float gi = sigmf(g.x + bb.x + pi[jg] * c_old);
        float gf = sigmf(g.y + bb.y + pf[jg] * c_old);
        float cn = gf * c_old + gi * tanhf(g.z + bb.z);
        float go = sigmf(g.w + bb.w + po[jg] * cn);
        c[ci] = cn;
        h_out[ci] = __float2bfloat16(go * tanhf(cn));
    }
}

// ---------------- decoder step (+ fused projection of previous h) ----------------
// grid (16, 9): bn 0..7 = gate tiles (state update for step t<=127);
// bn == 8 = projection columns of the INPUT h (valid for t>=1, writes x_raw[:, t-1, :]).
__global__ __launch_bounds__(256) void dec_step_kernel(
    const int t,
    const __hip_bfloat16* __restrict__ h_in,
    __hip_bfloat16* __restrict__ h_out,
    float* __restrict__ c,
    const __hip_bfloat16* __restrict__ Wp,
    const float* __restrict__ bp,
    const float* __restrict__ pi, const float* __restrict__ pf, const float* __restrict__ po,
    const float* __restrict__ ob,
    float* __restrict__ ox, float* __restrict__ oxr)
{
    __shared__ float glds[64 * 128];
    const int bn = blockIdx.y;
    const bool isproj = (bn == 8);
    if (isproj) { if (t == 0) return; } else { if (t == ND) return; }

    const int tid  = threadIdx.x;
    const int lane = tid & 63;
    const int wv   = tid >> 6;
    const int m0   = blockIdx.x * 64;
    const int lr   = lane & 15;
    const int lk   = (lane >> 4) << 3;

    f32x4 acc[4][2];
    #pragma unroll
    for (int mi = 0; mi < 4; ++mi)
        #pragma unroll
        for (int ni = 0; ni < 2; ++ni) acc[mi][ni] = {0.f, 0.f, 0.f, 0.f};

    const __hip_bfloat16* wb = Wp + (size_t)(bn * 128 + wv * 32 + lr) * KDEC + lk;
    const __hip_bfloat16* hb = h_in + (size_t)(m0 + lr) * NH + lk;

    #pragma unroll 4
    for (int kk = 0; kk < KDEC; kk += 32) {
        bf16x8 a[4], bf[2];
        #pragma unroll
        for (int mi = 0; mi < 4; ++mi)
            a[mi] = *reinterpret_cast<const bf16x8*>(hb + mi * 16 * NH + kk);
        #pragma unroll
        for (int ni = 0; ni < 2; ++ni)
            bf[ni] = *reinterpret_cast<const bf16x8*>(wb + ni * 16 * KDEC + kk);
        #pragma unroll
        for (int mi = 0; mi < 4; ++mi)
            #pragma unroll
            for (int ni = 0; ni < 2; ++ni)
                acc[mi][ni] = mfma16(a[mi], bf[ni], acc[mi][ni]);
    }

    if (isproj) {
        // columns: nl = local col index; valid projection cols are 0..63 (waves 0,1)
        #pragma unroll
        for (int ni = 0; ni < 2; ++ni) {
            int nl = wv * 32 + ni * 16 + lr;
            if (nl < NI) {
                #pragma unroll
                for (int mi = 0; mi < 4; ++mi)
                    #pragma unroll
                    for (int v = 0; v < 4; ++v) {
                        int row = m0 + 16 * mi + ((lane >> 4) << 2) + v;
                        float val = acc[mi][ni][v] + ob[nl];
                        size_t off = ((size_t)row * ND + (t - 1)) * NI + nl;
                        oxr[off] = val;
                        ox[off]  = sigmf(val);
                    }
            }
        }
        return;
    }

    #pragma unroll
    for (int mi = 0; mi < 4; ++mi)
        #pragma unroll
        for (int ni = 0; ni < 2; ++ni)
            #pragma unroll
            for (int v = 0; v < 4; ++v)
                glds[(16 * mi + ((lane >> 4) << 2) + v) * 128 + wv * 32 + ni * 16 + lr] = acc[mi][ni][v];
    __syncthreads();

    for (int idx = tid; idx < 64 * 32; idx += 256) {
        int r = idx >> 5, j = idx & 31;
        int jg = bn * 32 + j;
        float4 g  = *reinterpret_cast<const float4*>(&glds[r * 128 + 4 * j]);
        float4 bb = *reinterpret_cast<const float4*>(&bp[4 * jg]);
        int ci = (m0 + r) * NH + jg;
        float c_old = c[ci];
        float gi = sigmf(g.x + bb.x + pi[jg] * c_old);
        float gf = sigmf(g.y + bb.y + pf[jg] * c_old);
        float cn = gf * c_old + gi * tanhf(g.z + bb.z);
        float go = sigmf(g.w + bb.w + po[jg] * cn);
        c[ci] = cn;
        h_out[ci] = __float2bfloat16(go * tanhf(cn));
    }
}

// ---------------- middle: z = mu + exp(0.5*ls)*noise ----------------
__global__ void mid_kernel(const float* __restrict__ cenc, const float* __restrict__ noise,
                           float* __restrict__ cdec, float* __restrict__ oz,
                           float* __restrict__ omut, float* __restrict__ olst)
{
    int idx = blockIdx.x * 256 + threadIdx.x;  // < 262144
    int b = idx >> 8, h = idx & 255;
    float mu = cenc[b * NHE + h];
    float ls = cenc[b * NHE + NH + h];
    float zz = mu + expf(0.5f * ls) * noise[idx];
    omut[idx] = mu;
    olst[idx] = ls;
    oz[idx]   = zz;
    cdec[idx] = zz;
}

// ---------------- mixture params ----------------
__global__ void mix_kernel(const float* __restrict__ mu_in, const float* __restrict__ s2_in,
                           const float* __restrict__ phi_in,
                           float* __restrict__ mu_out, float* __restrict__ s2_out,
                           float* __restrict__ phi_out)
{
    int idx = blockIdx.x * 256 + threadIdx.x;  // < 2048
    mu_out[idx] = mu_in[idx];
    float x = s2_in[idx];
    s2_out[idx] = (x > 20.0f) ? x : log1pf(expf(x));
    if (idx == 0) {
        float m = phi_in[0];
        for (int k = 1; k < 8; ++k) m = fmaxf(m, phi_in[k]);
        float e[8], s = 0.0f;
        for (int k = 0; k < 8; ++k) { e[k] = expf(phi_in[k] - m); s += e[k]; }
        for (int k = 0; k < 8; ++k) phi_out[k] = e[k] / s;
    }
}

// ---------------- host ----------------
extern "C" void kernel_launch(void* const* d_in, const int* in_sizes, int n_in,
                              void* d_out, int out_size, void* d_ws, size_t ws_size,
                              hipStream_t stream)
{
    const float* X     = (const float*)d_in[0];
    const int*   W     = (const int*)d_in[1];
    const float* noise = (const float*)d_in[2];
    const float* A     = (const float*)d_in[3];
    const float* eWx   = (const float*)d_in[4];
    const float* eWh   = (const float*)d_in[5];
    const float* eb    = (const float*)d_in[6];
    const float* epi   = (const float*)d_in[7];
    const float* epf   = (const float*)d_in[8];
    const float* epo   = (const float*)d_in[9];
    const float* dWh   = (const float*)d_in[11];
    const float* db    = (const float*)d_in[12];
    const float* dpi   = (const float*)d_in[13];
    const float* dpf   = (const float*)d_in[14];
    const float* dpo   = (const float*)d_in[15];
    const float* ow    = (const float*)d_in[16];
    const float* ob    = (const float*)d_in[17];
    const float* muc   = (const float*)d_in[18];
    const float* s2c   = (const float*)d_in[19];
    const float* phic  = (const float*)d_in[20];

    float* out = (float*)d_out;
    float* o_x    = out;
    float* o_xraw = out + 8388608;
    float* o_muc  = out + 16777216;
    float* o_s2c  = out + 16779264;
    float* o_phic = out + 16781312;
    float* o_z    = out + 16781320;
    float* o_mut  = out + 17043464;
    float* o_lst  = out + 17305608;

    char* ws = (char*)d_ws;
    __hip_bfloat16* Wencp = (__hip_bfloat16*)(ws + 0);         // 2048*576*2 = 2359296
    __hip_bfloat16* Wdecp = (__hip_bfloat16*)(ws + 2359296);   // 1152*256*2 = 589824
    float*          bencp = (float*)(ws + 2949120);            // 2048*4
    float*          bdecp = (float*)(ws + 2957312);            // 1024*4 (+pad)
    __hip_bfloat16* Xb    = (__hip_bfloat16*)(ws + 2961408);   // 128*1024*64*2 = 16777216
    __hip_bfloat16* he0   = (__hip_bfloat16*)(ws + 19738624);  // 1024*512*2
    __hip_bfloat16* he1   = (__hip_bfloat16*)(ws + 20787200);  // 1024*512*2
    float*          cenc  = (float*)(ws + 21835776);           // 1024*512*4
    __hip_bfloat16* hd0   = (__hip_bfloat16*)(ws + 23932928);  // 1024*256*2
    __hip_bfloat16* hd1   = (__hip_bfloat16*)(ws + 24457216);  // 1024*256*2
    float*          cdec  = (float*)(ws + 24981504);           // 1024*256*4  (end 26030080)

    hipMemsetAsync(he0, 0, 1048576, stream);
    hipMemsetAsync(cenc, 0, 2097152, stream);
    hipMemsetAsync(hd0, 0, 524288, stream);

    pack_enc_kernel<<<dim3(3, 2048), 256, 0, stream>>>(eWx, eWh, eb, Wencp, bencp);
    pack_dec_kernel<<<dim3(1, 1152), 256, 0, stream>>>(dWh, ow, db, Wdecp, bdecp);
    pack_xb_kernel<<<32768, 256, 0, stream>>>(X, W, A, Xb);

    __hip_bfloat16* hb[2] = {he0, he1};
    for (int t = 0; t < ND; ++t) {
        enc_step_kernel<<<dim3(16, 16), 256, 0, stream>>>(
            Xb + (size_t)t * NB * NI, hb[t & 1], hb[(t & 1) ^ 1], cenc,
            Wencp, bencp, epi, epf, epo);
    }

    mid_kernel<<<1024, 256, 0, stream>>>(cenc, noise, cdec, o_z, o_mut, o_lst);
    mix_kernel<<<8, 256, 0, stream>>>(muc, s2c, phic, o_muc, o_s2c, o_phic);

    __hip_bfloat16* hdb[2] = {hd0, hd1};
    for (int t = 0; t <= ND; ++t) {
        dec_step_kernel<<<dim3(16, 9), 256, 0, stream>>>(
            t, hdb[t & 1], hdb[(t & 1) ^ 1], cdec, Wdecp, bdecp,
            dpi, dpf, dpo, ob, o_x, o_xraw);
    }
}

// Round 2
// 2768.157 us; speedup vs baseline: 1.3261x; 1.3261x over previous
//
#include <hip/hip_runtime.h>
#include <hip/hip_bf16.h>

typedef __attribute__((ext_vector_type(4))) float f32x4;
typedef __attribute__((ext_vector_type(8))) short bf16x8;

#define NB 1024   // batch
#define ND 128    // time steps
#define NI 64     // input dim
#define NH 256    // dec hidden
#define NHE 512   // enc hidden
#define KENC 576  // NI + NHE
#define NENC 2048 // 4*NHE
#define KDEC 256
#define LDSTR 648 // LDS A-tile stride (elements): 64*648*2 = 82944 B -> 1 block/CU

__device__ __forceinline__ float sigmf(float x) { return 1.0f / (1.0f + __expf(-x)); }
__device__ __forceinline__ float tanh_f(float x) { return 1.0f - 2.0f / (__expf(2.0f * x) + 1.0f); }

__device__ __forceinline__ f32x4 mfma16(bf16x8 a, bf16x8 b, f32x4 c) {
    return __builtin_amdgcn_mfma_f32_16x16x32_bf16(a, b, c, 0, 0, 0);
}

__device__ __forceinline__ void spin_ge(const int* p, int target) {
    int g = 0;
    while (__hip_atomic_load(p, __ATOMIC_RELAXED, __HIP_MEMORY_SCOPE_AGENT) < target) {
        __builtin_amdgcn_s_sleep(2);
        if (++g > (1 << 24)) break;   // deadlock bailout -> visible failure, no hang
    }
}

// 4x4 transpose within each lane-quad across regs v0..v3.
// In: MFMA frag a, elem v = C[4q+v][lr] (q=lane>>4, lr=lane&15).
// Out: lane holds gates g=0..3 of (row 4q+(lane&3), unit (lane>>2)&3).
__device__ __forceinline__ void quadtr(f32x4 a, int lane,
                                       float& z0, float& z1, float& z2, float& z3) {
    float x0 = a[0], x1 = a[1], x2 = a[2], x3 = a[3];
    float s0 = __shfl_xor(x0, 1), s1 = __shfl_xor(x1, 1),
          s2 = __shfl_xor(x2, 1), s3 = __shfl_xor(x3, 1);
    bool o1 = (lane & 1) != 0;
    float y0 = o1 ? s1 : x0;
    float y1 = o1 ? x1 : s0;
    float y2 = o1 ? s3 : x2;
    float y3 = o1 ? x3 : s2;
    float t0 = __shfl_xor(y0, 2), t1 = __shfl_xor(y1, 2),
          t2 = __shfl_xor(y2, 2), t3 = __shfl_xor(y3, 2);
    bool o2 = (lane & 2) != 0;
    z0 = o2 ? t2 : y0;
    z1 = o2 ? t3 : y1;
    z2 = o2 ? y2 : t0;
    z3 = o2 ? y3 : t1;
}

// ---------------- packing kernels (unchanged from round 0, passed) ----------------

__global__ void pack_enc_kernel(const float* __restrict__ Wx, const float* __restrict__ Wh,
                                const float* __restrict__ bsrc,
                                __hip_bfloat16* __restrict__ Wp, float* __restrict__ bp)
{
    int n = blockIdx.y;
    int k = blockIdx.x * 256 + threadIdx.x;
    int j = n >> 2, g = n & 3;
    int col = g * NHE + j;
    if (k < KENC) {
        float v = (k < NI) ? Wx[k * NENC + col] : Wh[(k - NI) * NENC + col];
        Wp[(size_t)n * KENC + k] = __float2bfloat16(v);
    }
    if (blockIdx.x == 0 && threadIdx.x == 0) bp[n] = bsrc[col];
}

__global__ void pack_dec_kernel(const float* __restrict__ Wh, const float* __restrict__ ow,
                                const float* __restrict__ bsrc,
                                __hip_bfloat16* __restrict__ Wp, float* __restrict__ bp)
{
    int n = blockIdx.y;          // 0..1151
    int k = threadIdx.x;         // 0..255
    float v;
    if (n < 1024) {
        int j = n >> 2, g = n & 3;
        int col = g * NH + j;
        v = Wh[k * 1024 + col];
        if (k == 0) bp[n] = bsrc[col];
    } else if (n < 1088) {
        v = ow[k * NI + (n - 1024)];
    } else {
        v = 0.0f;
    }
    Wp[(size_t)n * KDEC + k] = __float2bfloat16(v);
}

__global__ void pack_xb_kernel(const float* __restrict__ X, const int* __restrict__ W,
                               const float* __restrict__ A, __hip_bfloat16* __restrict__ Xb)
{
    int idx = blockIdx.x * 256 + threadIdx.x;
    int i = idx & 63;
    int t1 = idx >> 6;
    int b = t1 & 1023;
    int d = t1 >> 10;
    int src = (b * ND + d) * NI + i;
    float v = W[src] ? X[src] : A[d * NI + i];
    Xb[idx] = __float2bfloat16(v);
}

// ---------------- persistent encoder ----------------
// grid (16 m, 16 n), 512 threads (8 waves). Wave: 64 rows x 16 cols.
// B (weights) in registers for all 128 steps; A (x|h) staged in LDS per step;
// c in registers across steps; m-group flag sync.
__global__ __launch_bounds__(512, 2) void enc_persist(
    const __hip_bfloat16* __restrict__ Xb,
    __hip_bfloat16* __restrict__ h0buf, __hip_bfloat16* __restrict__ h1buf,
    float* __restrict__ cenc,
    const __hip_bfloat16* __restrict__ Wp, const float* __restrict__ bp,
    const float* __restrict__ pi, const float* __restrict__ pf, const float* __restrict__ po,
    int* __restrict__ wrflag)
{
    __shared__ __align__(16) unsigned short Alds[64][LDSTR];

    const int tid  = threadIdx.x;
    const int lane = tid & 63;
    const int wv   = tid >> 6;
    const int bm   = blockIdx.x;
    const int bn   = blockIdx.y;
    const int m0   = bm * 64;
    const int lr   = lane & 15;
    const int q    = lane >> 4;
    const int lk   = q * 8;

    // persistent weight fragments: col = bn*128 + wv*16 + lr
    const int col = bn * 128 + wv * 16 + lr;
    bf16x8 breg[18];
    #pragma unroll
    for (int i = 0; i < 18; ++i)
        breg[i] = *reinterpret_cast<const bf16x8*>(Wp + (size_t)col * KENC + i * 32 + lk);

    // per-lane epilogue params: unit j, gates bias, peepholes
    const int u = (lane >> 2) & 3;
    const int j = bn * 32 + wv * 4 + u;
    const float4 bb = *reinterpret_cast<const float4*>(bp + 4 * j);
    const float ppi = pi[j], ppf = pf[j], ppo = po[j];
    const int rowb = m0 + 4 * q + (lane & 3);

    float creg[4] = {0.f, 0.f, 0.f, 0.f};
    __hip_bfloat16* hb[2] = {h0buf, h1buf};

    for (int t = 0; t < ND; ++t) {
        if (t > 0 && tid == 0) {
            spin_ge(&wrflag[bm * ND + (t - 1)], 16);
            __builtin_amdgcn_fence(__ATOMIC_ACQUIRE, "agent");
        }
        __syncthreads();

        // stage A-tile: cols 0..63 = X_t, 64..575 = h_t
        {
            int row = tid >> 3, ch = tid & 7;
            *reinterpret_cast<bf16x8*>(&Alds[row][ch * 8]) =
                *reinterpret_cast<const bf16x8*>(Xb + ((size_t)t * NB + m0 + row) * NI + ch * 8);
        }
        const __hip_bfloat16* hsrc = hb[t & 1];
        #pragma unroll
        for (int it = 0; it < 8; ++it) {
            int idx = tid + it * 512;
            int row = idx >> 6, ch = idx & 63;
            *reinterpret_cast<bf16x8*>(&Alds[row][64 + ch * 8]) =
                *reinterpret_cast<const bf16x8*>(hsrc + (size_t)(m0 + row) * NHE + ch * 8);
        }
        __syncthreads();

        // K-loop
        f32x4 acc[4];
        #pragma unroll
        for (int mi = 0; mi < 4; ++mi) acc[mi] = {0.f, 0.f, 0.f, 0.f};
        #pragma unroll
        for (int i = 0; i < 18; ++i) {
            bf16x8 a[4];
            #pragma unroll
            for (int mi = 0; mi < 4; ++mi)
                a[mi] = *reinterpret_cast<const bf16x8*>(&Alds[16 * mi + lr][i * 32 + lk]);
            #pragma unroll
            for (int mi = 0; mi < 4; ++mi)
                acc[mi] = mfma16(a[mi], breg[i], acc[mi]);
        }

        // epilogue: in-register peephole update
        __hip_bfloat16* hdst = hb[(t + 1) & 1];
        #pragma unroll
        for (int mi = 0; mi < 4; ++mi) {
            float z0, z1, z2, z3;
            quadtr(acc[mi], lane, z0, z1, z2, z3);
            float c_old = creg[mi];
            float gi = sigmf(z0 + bb.x + ppi * c_old);
            float gf = sigmf(z1 + bb.y + ppf * c_old);
            float cn = gf * c_old + gi * tanh_f(z2 + bb.z);
            float go = sigmf(z3 + bb.w + ppo * cn);
            creg[mi] = cn;
            int row = rowb + 16 * mi;
            hdst[(size_t)row * NHE + j] = __float2bfloat16(go * tanh_f(cn));
            if (t == ND - 1) cenc[(size_t)row * NHE + j] = cn;
        }
        __syncthreads();

        if (tid == 0 && t < ND - 1) {
            __builtin_amdgcn_fence(__ATOMIC_RELEASE, "agent");
            __hip_atomic_fetch_add(&wrflag[bm * ND + t], 1, __ATOMIC_RELAXED, __HIP_MEMORY_SCOPE_AGENT);
        }
    }
}

// ---------------- persistent decoder (+ fused projection) ----------------
// grid (16 m, 9 n): bn 0..7 gate blocks, bn==8 projection block.
__global__ __launch_bounds__(512, 2) void dec_persist(
    __hip_bfloat16* __restrict__ hd0, __hip_bfloat16* __restrict__ hd1,
    const float* __restrict__ zdec,
    const __hip_bfloat16* __restrict__ Wp, const float* __restrict__ bp,
    const float* __restrict__ pi, const float* __restrict__ pf, const float* __restrict__ po,
    const float* __restrict__ ob,
    float* __restrict__ ox, float* __restrict__ oxr,
    int* __restrict__ wr2, int* __restrict__ prd)
{
    __shared__ __align__(16) unsigned short Alds[64][LDSTR]; // cols 0..255 used

    const int tid  = threadIdx.x;
    const int lane = tid & 63;
    const int wv   = tid >> 6;
    const int bm   = blockIdx.x;
    const int bn   = blockIdx.y;
    const int m0   = bm * 64;
    const int lr   = lane & 15;
    const int q    = lane >> 4;
    const int lk   = q * 8;

    __hip_bfloat16* hb[2] = {hd0, hd1};

    if (bn < 8) {
        // ---- gate blocks ----
        const int col = bn * 128 + wv * 16 + lr;
        bf16x8 breg[8];
        #pragma unroll
        for (int i = 0; i < 8; ++i)
            breg[i] = *reinterpret_cast<const bf16x8*>(Wp + (size_t)col * KDEC + i * 32 + lk);

        const int u = (lane >> 2) & 3;
        const int j = bn * 32 + wv * 4 + u;
        const float4 bb = *reinterpret_cast<const float4*>(bp + 4 * j);
        const float ppi = pi[j], ppf = pf[j], ppo = po[j];
        const int rowb = m0 + 4 * q + (lane & 3);

        float creg[4];
        #pragma unroll
        for (int mi = 0; mi < 4; ++mi)
            creg[mi] = zdec[(size_t)(rowb + 16 * mi) * NH + j];

        for (int t = 0; t < ND; ++t) {
            if (tid == 0) {
                if (t >= 1) spin_ge(&wr2[bm * ND + (t - 1)], 8);
                if (t >= 2) spin_ge(&prd[bm * ND + (t - 2)], 1);
                if (t >= 1) __builtin_amdgcn_fence(__ATOMIC_ACQUIRE, "agent");
            }
            __syncthreads();

            const __hip_bfloat16* hsrc = hb[t & 1];
            #pragma unroll
            for (int it = 0; it < 4; ++it) {
                int idx = tid + it * 512;
                int row = idx >> 5, ch = idx & 31;
                *reinterpret_cast<bf16x8*>(&Alds[row][ch * 8]) =
                    *reinterpret_cast<const bf16x8*>(hsrc + (size_t)(m0 + row) * NH + ch * 8);
            }
            __syncthreads();

            f32x4 acc[4];
            #pragma unroll
            for (int mi = 0; mi < 4; ++mi) acc[mi] = {0.f, 0.f, 0.f, 0.f};
            #pragma unroll
            for (int i = 0; i < 8; ++i) {
                bf16x8 a[4];
                #pragma unroll
                for (int mi = 0; mi < 4; ++mi)
                    a[mi] = *reinterpret_cast<const bf16x8*>(&Alds[16 * mi + lr][i * 32 + lk]);
                #pragma unroll
                for (int mi = 0; mi < 4; ++mi)
                    acc[mi] = mfma16(a[mi], breg[i], acc[mi]);
            }

            __hip_bfloat16* hdst = hb[(t + 1) & 1];
            #pragma unroll
            for (int mi = 0; mi < 4; ++mi) {
                float z0, z1, z2, z3;
                quadtr(acc[mi], lane, z0, z1, z2, z3);
                float c_old = creg[mi];
                float gi = sigmf(z0 + bb.x + ppi * c_old);
                float gf = sigmf(z1 + bb.y + ppf * c_old);
                float cn = gf * c_old + gi * tanh_f(z2 + bb.z);
                float go = sigmf(z3 + bb.w + ppo * cn);
                creg[mi] = cn;
                int row = rowb + 16 * mi;
                hdst[(size_t)row * NH + j] = __float2bfloat16(go * tanh_f(cn));
            }
            __syncthreads();

            if (tid == 0) {
                __builtin_amdgcn_fence(__ATOMIC_RELEASE, "agent");
                __hip_atomic_fetch_add(&wr2[bm * ND + t], 1, __ATOMIC_RELAXED, __HIP_MEMORY_SCOPE_AGENT);
            }
        }
    } else {
        // ---- projection block: x_raw[:, s, :] = h_{s+1} @ ow + ob ----
        bf16x8 breg[8];
        const int colw = 1024 + wv * 16 + lr;  // rows 1024..1151 of packed dec weights
        #pragma unroll
        for (int i = 0; i < 8; ++i)
            breg[i] = *reinterpret_cast<const bf16x8*>(Wp + (size_t)colw * KDEC + i * 32 + lk);
        const float obv = (wv < 4) ? ob[wv * 16 + lr] : 0.0f;

        for (int s = 0; s < ND; ++s) {
            if (tid == 0) {
                spin_ge(&wr2[bm * ND + s], 8);
                __builtin_amdgcn_fence(__ATOMIC_ACQUIRE, "agent");
            }
            __syncthreads();

            const __hip_bfloat16* hsrc = hb[(s + 1) & 1];
            #pragma unroll
            for (int it = 0; it < 4; ++it) {
                int idx = tid + it * 512;
                int row = idx >> 5, ch = idx & 31;
                *reinterpret_cast<bf16x8*>(&Alds[row][ch * 8]) =
                    *reinterpret_cast<const bf16x8*>(hsrc + (size_t)(m0 + row) * NH + ch * 8);
            }
            __syncthreads();

            // h-buffer reads done -> allow gates to overwrite it
            if (tid == 0)
                __hip_atomic_fetch_add(&prd[bm * ND + s], 1, __ATOMIC_RELAXED, __HIP_MEMORY_SCOPE_AGENT);

            if (wv < 4) {
                f32x4 acc[4];
                #pragma unroll
                for (int mi = 0; mi < 4; ++mi) acc[mi] = {0.f, 0.f, 0.f, 0.f};
                #pragma unroll
                for (int i = 0; i < 8; ++i) {
                    bf16x8 a[4];
                    #pragma unroll
                    for (int mi = 0; mi < 4; ++mi)
                        a[mi] = *reinterpret_cast<const bf16x8*>(&Alds[16 * mi + lr][i * 32 + lk]);
                    #pragma unroll
                    for (int mi = 0; mi < 4; ++mi)
                        acc[mi] = mfma16(a[mi], breg[i], acc[mi]);
                }
                int colp = wv * 16 + lr;
                #pragma unroll
                for (int mi = 0; mi < 4; ++mi) {
                    #pragma unroll
                    for (int v = 0; v < 4; ++v) {
                        int row = m0 + 16 * mi + 4 * q + v;
                        float val = acc[mi][v] + obv;
                        size_t off = (size_t)row * (ND * NI) + (size_t)s * NI + colp;
                        oxr[off] = val;
                        ox[off]  = sigmf(val);
                    }
                }
            }
        }
    }
}

// ---------------- middle: z = mu + exp(0.5*ls)*noise ----------------
__global__ void mid_kernel(const float* __restrict__ cenc, const float* __restrict__ noise,
                           float* __restrict__ zdec, float* __restrict__ oz,
                           float* __restrict__ omut, float* __restrict__ olst)
{
    int idx = blockIdx.x * 256 + threadIdx.x;  // < 262144
    int b = idx >> 8, h = idx & 255;
    float mu = cenc[b * NHE + h];
    float ls = cenc[b * NHE + NH + h];
    float zz = mu + expf(0.5f * ls) * noise[idx];
    omut[idx] = mu;
    olst[idx] = ls;
    oz[idx]   = zz;
    zdec[idx] = zz;
}

// ---------------- mixture params ----------------
__global__ void mix_kernel(const float* __restrict__ mu_in, const float* __restrict__ s2_in,
                           const float* __restrict__ phi_in,
                           float* __restrict__ mu_out, float* __restrict__ s2_out,
                           float* __restrict__ phi_out)
{
    int idx = blockIdx.x * 256 + threadIdx.x;  // < 2048
    mu_out[idx] = mu_in[idx];
    float x = s2_in[idx];
    s2_out[idx] = (x > 20.0f) ? x : log1pf(expf(x));
    if (idx == 0) {
        float m = phi_in[0];
        for (int k = 1; k < 8; ++k) m = fmaxf(m, phi_in[k]);
        float e[8], s = 0.0f;
        for (int k = 0; k < 8; ++k) { e[k] = expf(phi_in[k] - m); s += e[k]; }
        for (int k = 0; k < 8; ++k) phi_out[k] = e[k] / s;
    }
}

// ---------------- host ----------------
extern "C" void kernel_launch(void* const* d_in, const int* in_sizes, int n_in,
                              void* d_out, int out_size, void* d_ws, size_t ws_size,
                              hipStream_t stream)
{
    const float* X     = (const float*)d_in[0];
    const int*   W     = (const int*)d_in[1];
    const float* noise = (const float*)d_in[2];
    const float* A     = (const float*)d_in[3];
    const float* eWx   = (const float*)d_in[4];
    const float* eWh   = (const float*)d_in[5];
    const float* eb    = (const float*)d_in[6];
    const float* epi   = (const float*)d_in[7];
    const float* epf   = (const float*)d_in[8];
    const float* epo   = (const float*)d_in[9];
    const float* dWh   = (const float*)d_in[11];
    const float* db    = (const float*)d_in[12];
    const float* dpi   = (const float*)d_in[13];
    const float* dpf   = (const float*)d_in[14];
    const float* dpo   = (const float*)d_in[15];
    const float* ow    = (const float*)d_in[16];
    const float* ob    = (const float*)d_in[17];
    const float* muc   = (const float*)d_in[18];
    const float* s2c   = (const float*)d_in[19];
    const float* phic  = (const float*)d_in[20];

    float* out = (float*)d_out;
    float* o_x    = out;
    float* o_xraw = out + 8388608;
    float* o_muc  = out + 16777216;
    float* o_s2c  = out + 16779264;
    float* o_phic = out + 16781312;
    float* o_z    = out + 16781320;
    float* o_mut  = out + 17043464;
    float* o_lst  = out + 17305608;

    char* ws = (char*)d_ws;
    __hip_bfloat16* Wencp = (__hip_bfloat16*)(ws + 0);          // 2359296
    __hip_bfloat16* Wdecp = (__hip_bfloat16*)(ws + 2359296);    // 589824
    float*          bencp = (float*)(ws + 2949120);             // 8192
    float*          bdecp = (float*)(ws + 2957312);             // 8192 (pad)
    __hip_bfloat16* Xb    = (__hip_bfloat16*)(ws + 2965504);    // 16777216
    __hip_bfloat16* he0   = (__hip_bfloat16*)(ws + 19742720);   // 1048576
    __hip_bfloat16* he1   = (__hip_bfloat16*)(ws + 20791296);   // 1048576
    float*          cenc  = (float*)(ws + 21839872);            // 2097152
    __hip_bfloat16* hd0   = (__hip_bfloat16*)(ws + 23937024);   // 524288
    __hip_bfloat16* hd1   = (__hip_bfloat16*)(ws + 24461312);   // 524288
    float*          zdec  = (float*)(ws + 24985600);            // 1048576
    int*            encwr = (int*)(ws + 26034176);              // 8192
    int*            decwr = (int*)(ws + 26042368);              // 8192
    int*            decpr = (int*)(ws + 26050560);              // 8192  (end 26058752)

    hipMemsetAsync(he0, 0, 1048576, stream);
    hipMemsetAsync(hd0, 0, 524288, stream);
    hipMemsetAsync(encwr, 0, 24576, stream);  // encwr+decwr+decpr contiguous

    pack_enc_kernel<<<dim3(3, 2048), 256, 0, stream>>>(eWx, eWh, eb, Wencp, bencp);
    pack_dec_kernel<<<dim3(1, 1152), 256, 0, stream>>>(dWh, ow, db, Wdecp, bdecp);
    pack_xb_kernel<<<32768, 256, 0, stream>>>(X, W, A, Xb);

    enc_persist<<<dim3(16, 16), 512, 0, stream>>>(
        Xb, he0, he1, cenc, Wencp, bencp, epi, epf, epo, encwr);

    mid_kernel<<<1024, 256, 0, stream>>>(cenc, noise, zdec, o_z, o_mut, o_lst);
    mix_kernel<<<8, 256, 0, stream>>>(muc, s2c, phic, o_muc, o_s2c, o_phic);

    dec_persist<<<dim3(16, 9), 512, 0, stream>>>(
        hd0, hd1, zdec, Wdecp, bdecp, dpi, dpf, dpo, ob, o_x, o_xraw, decwr, decpr);
}